// Round 15
// baseline (72.690 us; speedup 1.0000x reference)
//
#include <hip/hip_runtime.h>
#include <hip/hip_bf16.h>
#include <math.h>

// ---------------------------------------------------------------------------
// ColorizationNet inference, 3 kernels:
//  1) fused_conv_prep_k: conv1..pool3 fully fused per 2x2 tile (r14: -35us)
//  2) base_acc_k: base[304] += w1[:, :32768] @ xconv (split-K 16, atomics)
//  3) chunk_k: per-chunk MLP, CPB=4 @1024 blocks. r15 change: h1 lives in a
//     per-chunk GLOBAL scratch row (h1g) instead of LDS. h2's 304 ds_read_b128
//     per wave (~12cyc each on the shared LDS pipe ~= 18us/CU at 12 waves) were
//     the measured bottleneck; uniform-address global float4 loads move that
//     traffic to the idle VMEM/L2 path.
// ---------------------------------------------------------------------------

#define CONV_FLAT 32768
#define H1_  304
#define H2_  176
#define OUT_ 48
#define CPB  4

// ws layout (float offsets)
#define WS_XC    196608     // 32*32*32   = 32768 (xconv)
#define WS_BASE  229376     // 320
#define WS_W1PCT 229696     // 18*304     = 5472
#define WS_W2Q   235168     // 76*176*4   = 53504  (w2 packed [k/4][t][4])
#define WS_W3Q   288672     // 44*48*4    = 8448   (w3 packed [k/4][t][4])
#define WS_H1G   297120     // 4096*304   = 1245184 (h1 per chunk, rows 1216B)

// ---------------- fused conv backbone (+ weight prep tail) ------------------
__global__ __launch_bounds__(256)
void fused_conv_prep_k(const float* __restrict__ x,
                       const float* __restrict__ c1w, const float* __restrict__ c1b,
                       const float* __restrict__ c2w, const float* __restrict__ c2b,
                       const float* __restrict__ c3w, const float* __restrict__ c3b,
                       const float* __restrict__ w1, const float* __restrict__ w2,
                       const float* __restrict__ w3, const float* __restrict__ b1,
                       float* __restrict__ xconv, float* __restrict__ w1pcT,
                       float* __restrict__ w2q, float* __restrict__ w3q,
                       float* __restrict__ base) {
    int tid = threadIdx.x;
    if (blockIdx.x >= 256) {        // ---- prep tail (209 blocks) ----
        int idx = (blockIdx.x - 256) * 256 + tid;
        if (idx < 304 * 176) {                     // w2 row-major [176][304]
            int t = idx / 304, k = idx - t * 304;
            w2q[(k >> 2) * (H2_ * 4) + t * 4 + (k & 3)] = w2[idx];
        }
        if (idx < 48 * 176) {                      // w3 row-major [48][176]
            int t = idx / 176, k = idx - t * 176;
            w3q[(k >> 2) * 192 + t * 4 + (k & 3)] = w3[idx];
        }
        if (idx < 304 * 18) {                      // w1[:, 32768+k]
            int t = idx / 18, k = idx - t * 18;
            w1pcT[k * 304 + t] = w1[(size_t)t * 32786 + 32768 + k];
        }
        if (idx < H1_) base[idx] = b1[idx];
        return;
    }
    int ti = blockIdx.x >> 4, tj = blockIdx.x & 15;

    __shared__ float xl[30][30];        // x halo
    __shared__ float c1l[8][14][14];    // c1 pooled halo
    __shared__ float c2l[16][6][6];     // c2 pooled halo

    for (int e = tid; e < 900; e += 256) {
        int a = e / 30, b = e - a * 30;
        int gy = 16 * ti - 7 + a, gx = 16 * tj - 7 + b;
        float v = 0.f;
        if ((unsigned)gy < 256u && (unsigned)gx < 256u) v = x[gy * 256 + gx];
        xl[a][b] = v;
    }
    __syncthreads();

    for (int e = tid; e < 1568; e += 256) {
        int c = e / 196, r = e - c * 196;
        int a = r / 14, b = r - a * 14;
        int gv = 8 * ti - 3 + a, gu = 8 * tj - 3 + b;
        float val = 0.f;
        if ((unsigned)gv < 128u && (unsigned)gu < 128u) {
            const float* wp = c1w + c * 9;
            float bias = c1b[c];
            float s00 = bias, s01 = bias, s10 = bias, s11 = bias;
#pragma unroll
            for (int ky = 0; ky < 3; ky++) {
#pragma unroll
                for (int kx = 0; kx < 3; kx++) {
                    float wv = wp[ky * 3 + kx];
                    s00 += xl[2 * a + 0 + ky][2 * b + 0 + kx] * wv;
                    s01 += xl[2 * a + 0 + ky][2 * b + 1 + kx] * wv;
                    s10 += xl[2 * a + 1 + ky][2 * b + 0 + kx] * wv;
                    s11 += xl[2 * a + 1 + ky][2 * b + 1 + kx] * wv;
                }
            }
            val = fmaxf(fmaxf(fmaxf(s00, s01), fmaxf(s10, s11)), 0.f);
        }
        c1l[c][a][b] = val;
    }
    __syncthreads();

    for (int e = tid; e < 576; e += 256) {
        int c = e / 36, r = e - c * 36;
        int a = r / 6, b = r - a * 6;
        int gsy = 4 * ti - 1 + a, gsx = 4 * tj - 1 + b;
        float val = 0.f;
        if ((unsigned)gsy < 64u && (unsigned)gsx < 64u) {
            float bias = c2b[c];
            float s00 = bias, s01 = bias, s10 = bias, s11 = bias;
            const float* wb = c2w + c * 72;
#pragma unroll
            for (int ic = 0; ic < 8; ic++) {
                const float* wp = wb + ic * 9;
#pragma unroll
                for (int ky = 0; ky < 3; ky++) {
#pragma unroll
                    for (int kx = 0; kx < 3; kx++) {
                        float wv = wp[ky * 3 + kx];
                        s00 += c1l[ic][2 * a + 0 + ky][2 * b + 0 + kx] * wv;
                        s01 += c1l[ic][2 * a + 0 + ky][2 * b + 1 + kx] * wv;
                        s10 += c1l[ic][2 * a + 1 + ky][2 * b + 0 + kx] * wv;
                        s11 += c1l[ic][2 * a + 1 + ky][2 * b + 1 + kx] * wv;
                    }
                }
            }
            val = fmaxf(fmaxf(fmaxf(s00, s01), fmaxf(s10, s11)), 0.f);
        }
        c2l[c][a][b] = val;
    }
    __syncthreads();

    if (tid < 128) {
        int oc = tid >> 2, ql = tid & 3;
        int qly = ql >> 1, qlx = ql & 1;
        float bias = c3b[oc];
        float s00 = bias, s01 = bias, s10 = bias, s11 = bias;
        const float* wb = c3w + oc * 144;
#pragma unroll
        for (int ic = 0; ic < 16; ic++) {
            const float* wp = wb + ic * 9;
#pragma unroll
            for (int ky = 0; ky < 3; ky++) {
#pragma unroll
                for (int kx = 0; kx < 3; kx++) {
                    float wv = wp[ky * 3 + kx];
                    s00 += c2l[ic][2 * qly + 0 + ky][2 * qlx + 0 + kx] * wv;
                    s01 += c2l[ic][2 * qly + 0 + ky][2 * qlx + 1 + kx] * wv;
                    s10 += c2l[ic][2 * qly + 1 + ky][2 * qlx + 0 + kx] * wv;
                    s11 += c2l[ic][2 * qly + 1 + ky][2 * qlx + 1 + kx] * wv;
                }
            }
        }
        float val = fmaxf(fmaxf(fmaxf(s00, s01), fmaxf(s10, s11)), 0.f);
        xconv[oc * 1024 + (2 * ti + qly) * 32 + (2 * tj + qlx)] = val;
    }
}

// split-K: base[row] += dot(w1[row, seg], xconv[seg]); base pre-init to b1
#define NSEG 16
#define SEGLEN (CONV_FLAT / NSEG)   // 2048 floats
__global__ void base_acc_k(const float* __restrict__ w1, const float* __restrict__ xconv,
                           float* __restrict__ base) {
    int row = blockIdx.x >> 4;
    int seg = blockIdx.x & 15;
    const float2* wr = (const float2*)(w1 + (size_t)row * 32786) + seg * (SEGLEN / 2);
    const float2* xc = (const float2*)(xconv) + seg * (SEGLEN / 2);
    float acc = 0.f;
#pragma unroll
    for (int i = 0; i < 4; i++) {
        float2 a = wr[threadIdx.x + i * 256];
        float2 v = xc[threadIdx.x + i * 256];
        acc += a.x * v.x + a.y * v.y;
    }
#pragma unroll
    for (int off = 32; off > 0; off >>= 1)
        acc += __shfl_down(acc, off, 64);
    __shared__ float red[4];
    int lane = threadIdx.x & 63, wid = threadIdx.x >> 6;
    if (lane == 0) red[wid] = acc;
    __syncthreads();
    if (threadIdx.x == 0)
        atomicAdd(&base[row], red[0] + red[1] + red[2] + red[3]);
}

// fused per-chunk MLP, 4 chunks/block, 1024 blocks.
// h1 staged in GLOBAL scratch (h1g) — keeps h2's broadcast reads off the
// LDS pipe (measured 12cyc/ds_read_b128 made LDS the h2 bottleneck).
__global__ void chunk_k(const float* __restrict__ x, const float* __restrict__ base,
                        const float* __restrict__ w1pcT, const float* __restrict__ w2q,
                        const float* __restrict__ b2, const float* __restrict__ w3q,
                        const float* __restrict__ b3, float* __restrict__ h1g,
                        float* __restrict__ out) {
    __shared__ float pc[CPB][18];
    __shared__ float h2s[CPB][H2_];
    int tid = threadIdx.x;
    int c0 = blockIdx.x * CPB;

    if (tid < CPB * 18) {
        int u = tid / 18, k = tid - u * 18;
        int c = c0 + u;
        int i = c >> 6, j = c & 63;
        float v;
        if (k == 0)      v = (float)(i * 4);
        else if (k == 1) v = (float)(j * 4);
        else {
            int kk = k - 2;
            int r = kk >> 2, cc = kk & 3;
            v = x[(i * 4 + r) * 256 + j * 4 + cc];
        }
        pc[u][k] = v;
    }
    __syncthreads();

    // h1: 304 outputs x 4 chunks -> global rows h1g[(c0+u)*304 + t]
    for (int t = tid; t < H1_; t += 256) {
        float bb = base[t];
        float acc[CPB];
#pragma unroll
        for (int u = 0; u < CPB; u++) acc[u] = bb;
#pragma unroll
        for (int k = 0; k < 18; k++) {
            float w = w1pcT[k * H1_ + t];
#pragma unroll
            for (int u = 0; u < CPB; u++) acc[u] += w * pc[u][k];
        }
#pragma unroll
        for (int u = 0; u < CPB; u++)
            h1g[(size_t)(c0 + u) * H1_ + t] = fmaxf(acc[u], 0.f);
    }
    __syncthreads();   // vmcnt drained before barrier -> h1g rows visible

    // h2: 176 outputs x 4 chunks; weights float4 from L2, h1 float4 from L2
    if (tid < H2_) {
        const float4* wq = (const float4*)w2q;   // [76][176] float4s
        const float4* h1r0 = (const float4*)(h1g + (size_t)(c0 + 0) * H1_);
        const float4* h1r1 = (const float4*)(h1g + (size_t)(c0 + 1) * H1_);
        const float4* h1r2 = (const float4*)(h1g + (size_t)(c0 + 2) * H1_);
        const float4* h1r3 = (const float4*)(h1g + (size_t)(c0 + 3) * H1_);
        float bb = b2[tid];
        float a0 = bb, a1 = bb, a2 = bb, a3 = bb;
#pragma unroll 4
        for (int g = 0; g < 76; g++) {
            float4 w = wq[g * H2_ + tid];
            float4 h0 = h1r0[g];
            float4 h1v = h1r1[g];
            float4 h2v = h1r2[g];
            float4 h3 = h1r3[g];
            a0 += w.x * h0.x + w.y * h0.y + w.z * h0.z + w.w * h0.w;
            a1 += w.x * h1v.x + w.y * h1v.y + w.z * h1v.z + w.w * h1v.w;
            a2 += w.x * h2v.x + w.y * h2v.y + w.z * h2v.z + w.w * h2v.w;
            a3 += w.x * h3.x + w.y * h3.y + w.z * h3.z + w.w * h3.w;
        }
        h2s[0][tid] = fmaxf(a0, 0.f);
        h2s[1][tid] = fmaxf(a1, 0.f);
        h2s[2][tid] = fmaxf(a2, 0.f);
        h2s[3][tid] = fmaxf(a3, 0.f);
    }
    __syncthreads();

    // out: 48 outputs x 4 chunks = 192 threads
    if (tid < CPB * OUT_) {
        int u = tid / OUT_, t = tid - u * OUT_;
        const float4* wq = (const float4*)w3q;   // [44][48] float4s
        float acc = b3[t];
#pragma unroll 4
        for (int g = 0; g < 44; g++) {
            float4 w = wq[g * OUT_ + t];
            float4 h = *(const float4*)&h2s[u][g * 4];
            acc += w.x * h.x + w.y * h.y + w.z * h.z + w.w * h.w;
        }
        out[(size_t)(c0 + u) * OUT_ + t] = 1.f / (1.f + expf(-acc));
    }
}

extern "C" void kernel_launch(void* const* d_in, const int* in_sizes, int n_in,
                              void* d_out, int out_size, void* d_ws, size_t ws_size,
                              hipStream_t stream) {
    const float* x    = (const float*)d_in[0];
    const float* c1_w = (const float*)d_in[1];
    const float* c1_b = (const float*)d_in[2];
    const float* c2_w = (const float*)d_in[3];
    const float* c2_b = (const float*)d_in[4];
    const float* c3_w = (const float*)d_in[5];
    const float* c3_b = (const float*)d_in[6];
    const float* w1   = (const float*)d_in[7];
    const float* b1   = (const float*)d_in[8];
    const float* w2   = (const float*)d_in[9];
    const float* b2   = (const float*)d_in[10];
    const float* w3   = (const float*)d_in[11];
    const float* b3   = (const float*)d_in[12];
    float* out = (float*)d_out;
    float* ws  = (float*)d_ws;

    float* xconv  = ws + WS_XC;
    float* base   = ws + WS_BASE;
    float* w1pcT  = ws + WS_W1PCT;
    float* w2q    = ws + WS_W2Q;
    float* w3q    = ws + WS_W3Q;
    float* h1g    = ws + WS_H1G;

    fused_conv_prep_k<<<256 + 209, 256, 0, stream>>>(
        x, c1_w, c1_b, c2_w, c2_b, c3_w, c3_b, w1, w2, w3, b1,
        xconv, w1pcT, w2q, w3q, base);
    base_acc_k<<<H1_ * NSEG, 256, 0, stream>>>(w1, xconv, base);
    chunk_k<<<1024, 256, 0, stream>>>(x, base, w1pcT, w2q, b2, w3q, b3, h1g, out);
}